// Round 17
// baseline (319.225 us; speedup 1.0000x reference)
//
#include <hip/hip_runtime.h>
#include <math.h>

namespace {

constexpr int kT = 1024;
constexpr int kH = 1024;
constexpr int kNQ = 16;
constexpr int kNKV = 4;
constexpr int kD = 64;
constexpr int kQKV = (kNQ + 2 * kNKV) * kD;   // 1536
constexpr int kIDense = 4096;
constexpr int kIMoe = 512;
constexpr int kE = 8;
constexpr float kEps = 1e-6f;
constexpr long kTH = (long)kT * kH;

typedef __attribute__((ext_vector_type(8))) short short8;
typedef __attribute__((ext_vector_type(4))) float f32x4;

__device__ __forceinline__ ushort f2bf(float f) {
    union { float f; uint32_t u; } v; v.f = f;
    uint32_t r = (v.u + 0x7fffu + ((v.u >> 16) & 1u)) >> 16;
    return (ushort)r;
}
__device__ __forceinline__ void gload16(const void* g, void* l) {
    __builtin_amdgcn_global_load_lds(
        (const __attribute__((address_space(1))) void*)g,
        (__attribute__((address_space(3))) void*)l, 16, 0, 0);
}

// ---------------------------------------------------------------------------
// add + RMSNorm with fused nparts-sum; optionally fused MoE router
// ---------------------------------------------------------------------------
__global__ __launch_bounds__(256) void add_rmsnorm_kernel(
    const float* __restrict__ xP, int nparts, const float* __restrict__ res,
    const float* __restrict__ w, float* __restrict__ h32,
    ushort* __restrict__ h16, float* __restrict__ r_out,
    const float* __restrict__ gate_w, float* __restrict__ combine)
{
    __shared__ float red[4];
    __shared__ float gred[4][kE];
    const int t = blockIdx.x;
    const int i = threadIdx.x;
    const size_t base = (size_t)t * kH;
    float4 s = reinterpret_cast<const float4*>(res + base)[i];
    for (int p = 0; p < nparts; p++) {
        float4 a = reinterpret_cast<const float4*>(xP + p * kTH + base)[i];
        s.x += a.x; s.y += a.y; s.z += a.z; s.w += a.w;
    }
    reinterpret_cast<float4*>(r_out + base)[i] = s;
    float ss = s.x * s.x + s.y * s.y + s.z * s.z + s.w * s.w;
    #pragma unroll
    for (int off = 32; off > 0; off >>= 1) ss += __shfl_down(ss, off);
    if ((i & 63) == 0) red[i >> 6] = ss;
    __syncthreads();
    const float tot = red[0] + red[1] + red[2] + red[3];
    const float inv = rsqrtf(tot * (1.0f / kH) + kEps);
    float4 wv = reinterpret_cast<const float4*>(w)[i];
    float4 o = make_float4(s.x * inv * wv.x, s.y * inv * wv.y,
                           s.z * inv * wv.z, s.w * inv * wv.w);
    reinterpret_cast<float4*>(h32 + base)[i] = o;
    ushort4 u;
    u.x = f2bf(o.x); u.y = f2bf(o.y); u.z = f2bf(o.z); u.w = f2bf(o.w);
    reinterpret_cast<ushort4*>(h16 + base)[i] = u;

    if (gate_w != nullptr) {   // fused router (uniform branch)
        float le[kE];
        const float* gw = gate_w + (size_t)(i * 4) * kE;
        #pragma unroll
        for (int e = 0; e < kE; e++)
            le[e] = o.x * gw[e] + o.y * gw[kE + e] +
                    o.z * gw[2 * kE + e] + o.w * gw[3 * kE + e];
        #pragma unroll
        for (int e = 0; e < kE; e++) {
            #pragma unroll
            for (int off = 32; off > 0; off >>= 1)
                le[e] += __shfl_down(le[e], off);
        }
        if ((i & 63) == 0) {
            #pragma unroll
            for (int e = 0; e < kE; e++) gred[i >> 6][e] = le[e];
        }
        __syncthreads();
        if (i == 0) {
            float p[kE];
            float mx = -1e30f;
            #pragma unroll
            for (int e = 0; e < kE; e++) {
                p[e] = gred[0][e] + gred[1][e] + gred[2][e] + gred[3][e];
                mx = fmaxf(mx, p[e]);
            }
            float sum = 0.0f;
            #pragma unroll
            for (int e = 0; e < kE; e++) { p[e] = __expf(p[e] - mx); sum += p[e]; }
            const float invs = 1.0f / sum;
            #pragma unroll
            for (int e = 0; e < kE; e++) p[e] *= invs;
            int i1 = 0;
            #pragma unroll
            for (int e = 1; e < kE; e++) if (p[e] > p[i1]) i1 = e;
            int i2 = (i1 == 0) ? 1 : 0;
            #pragma unroll
            for (int e = 0; e < kE; e++) if (e != i1 && p[e] > p[i2]) i2 = e;
            #pragma unroll
            for (int e = 0; e < kE; e++)
                combine[(size_t)t * kE + e] =
                    (e == i1) ? p[i1] : (e == i2) ? p[i2] : 0.0f;
        }
    }
}

// ---------------------------------------------------------------------------
// Fast transpose + f32 -> bf16
// ---------------------------------------------------------------------------
__global__ __launch_bounds__(256) void transpose_bf16_kernel(
    const float* __restrict__ W, ushort* __restrict__ WT,
    int R, int Cn, int ld_w, long w_z_stride, long wt_z_stride)
{
    __shared__ float tile[64 * 65];
    const int z = blockIdx.z;
    const float* Wz = W + (size_t)z * w_z_stride;
    ushort* WTz = WT + (size_t)z * wt_z_stride;
    const int r0 = blockIdx.y * 64;
    const int c0 = blockIdx.x * 64;
    const int tid = threadIdx.x;
    const int lr = tid >> 4;
    const int lc = (tid & 15) * 4;
    #pragma unroll
    for (int p = 0; p < 4; p++) {
        const int row = p * 16 + lr;
        float4 v = *reinterpret_cast<const float4*>(
            &Wz[(size_t)(r0 + row) * ld_w + c0 + lc]);
        tile[row * 65 + lc + 0] = v.x;
        tile[row * 65 + lc + 1] = v.y;
        tile[row * 65 + lc + 2] = v.z;
        tile[row * 65 + lc + 3] = v.w;
    }
    __syncthreads();
    const int ocl = tid >> 2;
    const int q = tid & 3;
    ushort u[16];
    #pragma unroll
    for (int e = 0; e < 16; e++)
        u[e] = f2bf(tile[(q * 16 + e) * 65 + ocl]);
    ushort* dst = &WTz[(size_t)(c0 + ocl) * R + r0 + q * 16];
    *reinterpret_cast<short8*>(dst) = *reinterpret_cast<short8*>(&u[0]);
    *reinterpret_cast<short8*>(dst + 8) = *reinterpret_cast<short8*>(&u[8]);
}

// ---------------------------------------------------------------------------
// bf16 MFMA GEMM, 64x128 tile, BK=64, 512 thr (8 waves 2m x 4n) — ALL GEMMs
// ---------------------------------------------------------------------------
template <bool GATED>
__global__ __launch_bounds__(512) void mgemm128_kernel(
    const ushort* __restrict__ A, const ushort* __restrict__ B,
    float* __restrict__ Cf, ushort* __restrict__ C16,
    const float* __restrict__ scale,
    int lda, int ldb, int ldc, int kc,
    int gate_off_rows, long b_z_stride, int c_z_col, int k_z_off,
    int scale_stride, long c_fstride)
{
    __shared__ __align__(16) ushort As[64 * 64];
    __shared__ __align__(16) ushort Bs[128 * 64];
    __shared__ __align__(16) ushort Us[GATED ? 128 * 64 : 8];

    const int z = blockIdx.z;
    const int gy = gridDim.y;
    const int nf = gridDim.x * gy;
    const int fid = blockIdx.x + gridDim.x * blockIdx.y;
    const int qq = nf >> 3;
    const int id2 = (fid & 7) * qq + (fid >> 3);
    const int m0 = (id2 % gy) * 64;
    const int n0 = (id2 / gy) * 128;

    const int tid = threadIdx.x;
    const ushort* Bz = B + (size_t)z * b_z_stride;
    const int k0 = z * k_z_off;

    const int sr = tid >> 3;
    const int sc = tid & 7;

    const int lane = tid & 63;
    const int wave = tid >> 6;
    const int wr = (wave >> 2) * 32;
    const int wc = (wave & 3) * 32;
    const int lrow = lane & 15;
    const int lg = lane >> 4;

    f32x4 accg[2][2] = {};
    f32x4 accu[2][2] = {};

    for (int kk0 = 0; kk0 < kc; kk0 += 64) {
        const int kbase = k0 + kk0;
        {
            const int csA = (sc + (sr & 7)) & 7;
            gload16(A + (size_t)(m0 + sr) * lda + kbase + csA * 8,
                    (char*)As + tid * 16);
        }
        #pragma unroll
        for (int c = 0; c < 2; c++) {
            const int row = c * 64 + sr;
            const int cs = (sc + (row & 7)) & 7;
            gload16(Bz + (size_t)(n0 + row) * ldb + kbase + cs * 8,
                    (char*)Bs + c * 8192 + tid * 16);
            if constexpr (GATED)
                gload16(Bz + (size_t)(gate_off_rows + n0 + row) * ldb + kbase + cs * 8,
                        (char*)Us + c * 8192 + tid * 16);
        }
        __syncthreads();

        short8 af[2][2], bfr[2][2];
        #pragma unroll
        for (int mf = 0; mf < 2; mf++)
            #pragma unroll
            for (int kk = 0; kk < 2; kk++) {
                const int r = wr + mf * 16 + lrow;
                const int sl = ((kk * 4 + lg) - (r & 7)) & 7;
                af[mf][kk] = *reinterpret_cast<const short8*>(
                    (const char*)As + r * 128 + sl * 16);
            }
        #pragma unroll
        for (int nf2 = 0; nf2 < 2; nf2++)
            #pragma unroll
            for (int kk = 0; kk < 2; kk++) {
                const int n = wc + nf2 * 16 + lrow;
                const int sl = ((kk * 4 + lg) - (n & 7)) & 7;
                bfr[nf2][kk] = *reinterpret_cast<const short8*>(
                    (const char*)Bs + n * 128 + sl * 16);
            }
        #pragma unroll
        for (int mf = 0; mf < 2; mf++)
            #pragma unroll
            for (int nf2 = 0; nf2 < 2; nf2++)
                #pragma unroll
                for (int kk = 0; kk < 2; kk++)
                    accg[mf][nf2] = __builtin_amdgcn_mfma_f32_16x16x32_bf16(
                        af[mf][kk], bfr[nf2][kk], accg[mf][nf2], 0, 0, 0);
        if constexpr (GATED) {
            short8 uf[2][2];
            #pragma unroll
            for (int nf2 = 0; nf2 < 2; nf2++)
                #pragma unroll
                for (int kk = 0; kk < 2; kk++) {
                    const int n = wc + nf2 * 16 + lrow;
                    const int sl = ((kk * 4 + lg) - (n & 7)) & 7;
                    uf[nf2][kk] = *reinterpret_cast<const short8*>(
                        (const char*)Us + n * 128 + sl * 16);
                }
            #pragma unroll
            for (int mf = 0; mf < 2; mf++)
                #pragma unroll
                for (int nf2 = 0; nf2 < 2; nf2++)
                    #pragma unroll
                    for (int kk = 0; kk < 2; kk++)
                        accu[mf][nf2] = __builtin_amdgcn_mfma_f32_16x16x32_bf16(
                            af[mf][kk], uf[nf2][kk], accu[mf][nf2], 0, 0, 0);
        }
        __syncthreads();
    }

    const int r4 = (lane >> 4) * 4;
    const int cl = lane & 15;
    const int ccol = z * c_z_col;
    float* Cfz = Cf ? Cf + (size_t)z * c_fstride : nullptr;
    #pragma unroll
    for (int mf = 0; mf < 2; mf++) {
        #pragma unroll
        for (int nf2 = 0; nf2 < 2; nf2++) {
            #pragma unroll
            for (int j = 0; j < 4; j++) {
                const int row = m0 + wr + mf * 16 + r4 + j;
                const int col = ccol + n0 + wc + nf2 * 16 + cl;
                if constexpr (GATED) {
                    const float g = accg[mf][nf2][j];
                    const float u = accu[mf][nf2][j];
                    const float sv =
                        scale ? scale[(size_t)row * scale_stride + z] : 1.0f;
                    const float h = (g / (1.0f + __expf(-g))) * u * sv;
                    C16[(size_t)row * ldc + col] = f2bf(h);
                } else {
                    Cfz[(size_t)row * ldc + col] = accg[mf][nf2][j];
                }
            }
        }
    }
}

// ---------------------------------------------------------------------------
// RoPE + bf16 pack
// ---------------------------------------------------------------------------
__global__ __launch_bounds__(256) void rope_pack_kernel(
    const float* __restrict__ qkv, const int* __restrict__ positions,
    ushort* __restrict__ Qb, ushort* __restrict__ Kb)
{
    const int t = blockIdx.x;
    const float pos = (float)positions[t];
    for (int item = threadIdx.x; item < (kNQ + kNKV) * 32; item += 256) {
        const int head = item >> 5;
        const int i = item & 31;
        const float inv_freq = powf(10000.0f, -(float)i * (1.0f / 32.0f));
        const float f = pos * inv_freq;
        float sv, cv;
        sincosf(f, &sv, &cv);
        const size_t off = (size_t)t * kQKV + head * kD;
        const float x1 = qkv[off + i];
        const float x2 = qkv[off + 32 + i];
        const float r1 = x1 * cv - x2 * sv;
        const float r2 = x2 * cv + x1 * sv;
        if (head < kNQ) {
            ushort* q = Qb + ((size_t)head * kT + t) * kD;
            q[i] = f2bf(r1 * 0.125f);
            q[i + 32] = f2bf(r2 * 0.125f);
        } else {
            ushort* k = Kb + ((size_t)(head - kNQ) * kT + t) * kD;
            k[i] = f2bf(r1);
            k[i + 32] = f2bf(r2);
        }
    }
}

// ---------------------------------------------------------------------------
// MFMA flash attention, KV-SPLIT (z=2) — r12 structure
// ---------------------------------------------------------------------------
__global__ __launch_bounds__(256) void attn_mfma_kernel(
    const ushort* __restrict__ Qb, const ushort* __restrict__ Kb,
    const ushort* __restrict__ Vt, float* __restrict__ Opart,
    float* __restrict__ mlpart)
{
    __shared__ __align__(16) ushort Qs[64 * 64];
    __shared__ __align__(16) ushort Ks[64 * 64];
    __shared__ __align__(16) ushort Vs[64 * 64];
    __shared__ __align__(16) ushort Ps[64 * 64];
    const int tid = threadIdx.x;
    const int qbi = (int)gridDim.x - 1 - blockIdx.x;
    const int qb = qbi * 64;
    const int hq = blockIdx.y;
    const int zp = blockIdx.z;
    const int kvh = hq >> 2;

    const int nt = qbi + 1;
    const int halfc = (nt + 1) >> 1;
    const int sbeg = zp ? halfc : 0;
    const int send = zp ? nt : halfc;

    float* Oz = Opart + (((size_t)zp * kNQ + hq) * kT + qb) * kD;
    float* mlz = mlpart + (((size_t)zp * kNQ + hq) * kT + qb) * 2;

    if (sbeg >= send) {
        for (int i = tid; i < 64 * kD; i += 256) Oz[(i >> 6) * kD + (i & 63)] = 0.f;
        for (int i = tid; i < 64; i += 256) { mlz[i * 2] = -1e30f; mlz[i * 2 + 1] = 0.f; }
        return;
    }

    const int lane = tid & 63;
    const int wave = tid >> 6;
    const int lrow = lane & 15;
    const int g = lane >> 4;
    const int srow = tid >> 3;
    const int sx = tid & 7;
    const ushort* Qg = Qb + ((size_t)hq * kT + qb) * kD;
    const ushort* Kg = Kb + (size_t)kvh * kT * kD;
    const ushort* Vg = Vt + (size_t)kvh * kD * kT;
    const int xr = (lrow & 7) << 4;

    #pragma unroll
    for (int c = 0; c < 2; c++) {
        const int row = c * 32 + srow;
        gload16(Qg + (size_t)row * kD + ((sx ^ (row & 7)) * 8),
                (char*)Qs + c * 4096 + tid * 16);
    }
    __syncthreads();
    short8 qf[2];
    #pragma unroll
    for (int kk = 0; kk < 2; kk++)
        qf[kk] = *reinterpret_cast<const short8*>(
            (const char*)Qs + (16 * wave + lrow) * 128 + ((kk * 64 + g * 16) ^ xr));

    f32x4 oacc[4] = {};
    float mrow = -1e30f, lsum = 0.0f;

    for (int ti = sbeg; ti < send; ++ti) {
        const int s0 = ti * 64;
        __syncthreads();
        #pragma unroll
        for (int c = 0; c < 2; c++) {
            const int row = c * 32 + srow;
            gload16(Kg + (size_t)(s0 + row) * kD + ((sx ^ (row & 7)) * 8),
                    (char*)Ks + c * 4096 + tid * 16);
            gload16(Vg + (size_t)row * kT + s0 + ((sx ^ (row & 7)) * 8),
                    (char*)Vs + c * 4096 + tid * 16);
        }
        __syncthreads();

        f32x4 sacc[4] = {};
        #pragma unroll
        for (int nf = 0; nf < 4; nf++) {
            #pragma unroll
            for (int kk = 0; kk < 2; kk++) {
                short8 kf = *reinterpret_cast<const short8*>(
                    (const char*)Ks + (nf * 16 + lrow) * 128 + ((kk * 64 + g * 16) ^ xr));
                sacc[nf] = __builtin_amdgcn_mfma_f32_16x16x32_bf16(
                    kf, qf[kk], sacc[nf], 0, 0, 0);
            }
        }

        const bool diag = (s0 == qb);
        float pv[16];
        float mloc = -1e30f;
        #pragma unroll
        for (int nf = 0; nf < 4; nf++)
            #pragma unroll
            for (int j = 0; j < 4; j++) {
                float s = sacc[nf][j];
                if (diag && (nf * 16 + g * 4 + j > 16 * wave + lrow)) s = -1e30f;
                pv[nf * 4 + j] = s;
                mloc = fmaxf(mloc, s);
            }
        mloc = fmaxf(mloc, __shfl_xor(mloc, 16));
        mloc = fmaxf(mloc, __shfl_xor(mloc, 32));
        const float mnew = fmaxf(mrow, mloc);
        const float alpha = __expf(mrow - mnew);
        float psum = 0.0f;
        #pragma unroll
        for (int j = 0; j < 16; j++) { pv[j] = __expf(pv[j] - mnew); psum += pv[j]; }
        psum += __shfl_xor(psum, 16);
        psum += __shfl_xor(psum, 32);
        lsum = lsum * alpha + psum;
        mrow = mnew;

        const int prow = 16 * wave + lrow;
        #pragma unroll
        for (int nf = 0; nf < 4; nf++)
            #pragma unroll
            for (int jp = 0; jp < 2; jp++) {
                uint32_t pk = (uint32_t)f2bf(pv[nf * 4 + jp * 2]) |
                              ((uint32_t)f2bf(pv[nf * 4 + jp * 2 + 1]) << 16);
                *reinterpret_cast<uint32_t*>(
                    (char*)Ps + prow * 128 + ((nf * 32 + g * 8 + jp * 4) ^ xr)) = pk;
            }

        float aj[4];
        #pragma unroll
        for (int j = 0; j < 4; j++) aj[j] = __shfl(alpha, g * 4 + j);
        #pragma unroll
        for (int nf = 0; nf < 4; nf++)
            #pragma unroll
            for (int j = 0; j < 4; j++) oacc[nf][j] *= aj[j];

        short8 paf[2];
        #pragma unroll
        for (int kk = 0; kk < 2; kk++)
            paf[kk] = *reinterpret_cast<const short8*>(
                (const char*)Ps + prow * 128 + ((kk * 64 + g * 16) ^ xr));
        #pragma unroll
        for (int nf = 0; nf < 4; nf++)
            #pragma unroll
            for (int kk = 0; kk < 2; kk++) {
                short8 vf = *reinterpret_cast<const short8*>(
                    (const char*)Vs + (nf * 16 + lrow) * 128 + ((kk * 64 + g * 16) ^ xr));
                oacc[nf] = __builtin_amdgcn_mfma_f32_16x16x32_bf16(
                    paf[kk], vf, oacc[nf], 0, 0, 0);
            }
    }

    #pragma unroll
    for (int nf = 0; nf < 4; nf++)
        #pragma unroll
        for (int j = 0; j < 4; j++)
            Oz[(16 * wave + g * 4 + j) * kD + nf * 16 + lrow] = oacc[nf][j];
    if (g == 0) {
        mlz[(16 * wave + lrow) * 2 + 0] = mrow;
        mlz[(16 * wave + lrow) * 2 + 1] = lsum;
    }
}

// ---------------------------------------------------------------------------
// Merge 2 KV-split partials -> normalized bf16 attn output
// ---------------------------------------------------------------------------
__global__ __launch_bounds__(256) void attn_merge_kernel(
    const float* __restrict__ Opart, const float* __restrict__ mlpart,
    ushort* __restrict__ attn_o)
{
    const int trow = blockIdx.x;
    const int tid = threadIdx.x;
    const int head = tid >> 4;
    const int c4 = (tid & 15) * 4;
    const size_t i0 = ((size_t)head * kT + trow);
    const size_t i1 = (((size_t)kNQ + head) * kT + trow);
    const float m0 = mlpart[i0 * 2], l0 = mlpart[i0 * 2 + 1];
    const float m1 = mlpart[i1 * 2], l1 = mlpart[i1 * 2 + 1];
    const float m = fmaxf(m0, m1);
    const float e0 = __expf(m0 - m), e1 = __expf(m1 - m);
    const float inv = 1.0f / (l0 * e0 + l1 * e1);
    float4 a = *reinterpret_cast<const float4*>(&Opart[i0 * kD + c4]);
    float4 b = *reinterpret_cast<const float4*>(&Opart[i1 * kD + c4]);
    ushort4 u;
    u.x = f2bf((a.x * e0 + b.x * e1) * inv);
    u.y = f2bf((a.y * e0 + b.y * e1) * inv);
    u.z = f2bf((a.z * e0 + b.z * e1) * inv);
    u.w = f2bf((a.w * e0 + b.w * e1) * inv);
    *reinterpret_cast<ushort4*>(
        &attn_o[(size_t)trow * (kNQ * kD) + head * kD + c4]) = u;
}

// ---------------------------------------------------------------------------
// final: out[0:TH] = sum(mlpP[0..3]) + sum(scP[0..3]); out[TH:] = r
// ---------------------------------------------------------------------------
__global__ __launch_bounds__(256) void final_out_kernel(
    const float* __restrict__ mlpP, const float* __restrict__ scP,
    const float* __restrict__ r, float* __restrict__ out)
{
    const int i = blockIdx.x * 256 + threadIdx.x;
    float4 s = make_float4(0.f, 0.f, 0.f, 0.f);
    #pragma unroll
    for (int p = 0; p < 4; p++) {
        float4 a = reinterpret_cast<const float4*>(mlpP + p * kTH)[i];
        float4 b = reinterpret_cast<const float4*>(scP + p * kTH)[i];
        s.x += a.x + b.x; s.y += a.y + b.y; s.z += a.z + b.z; s.w += a.w + b.w;
    }
    reinterpret_cast<float4*>(out)[i] = s;
    reinterpret_cast<float4*>(out + kTH)[i] =
        reinterpret_cast<const float4*>(r)[i];
}

}  // namespace

extern "C" void kernel_launch(void* const* d_in, const int* in_sizes, int n_in,
                              void* d_out, int out_size, void* d_ws, size_t ws_size,
                              hipStream_t stream) {
    (void)in_sizes; (void)n_in; (void)out_size; (void)ws_size;
    const float* hidden   = (const float*)d_in[0];
    const float* residual = (const float*)d_in[1];
    const int*   positions= (const int*)d_in[2];
    const float* ln0_w    = (const float*)d_in[3];
    const float* pa0_w    = (const float*)d_in[4];
    const float* ln1_w    = (const float*)d_in[5];
    const float* pa1_w    = (const float*)d_in[6];
    const float* qkv0_w   = (const float*)d_in[7];
    const float* o0_w     = (const float*)d_in[8];
    const float* qkv1_w   = (const float*)d_in[9];
    const float* o1_w     = (const float*)d_in[10];
    const float* gu0_w    = (const float*)d_in[11];
    const float* dn0_w    = (const float*)d_in[12];
    const float* gu1_w    = (const float*)d_in[13];
    const float* dn1_w    = (const float*)d_in[14];
    const float* gate_w   = (const float*)d_in[15];
    const float* w13      = (const float*)d_in[16];
    const float* w2       = (const float*)d_in[17];
    float* out_h = (float*)d_out;

    char* wsb = (char*)d_ws;
    float*  r_buf   = (float*)(wsb + (0ull  << 20));   // 4 MB
    float*  h32     = (float*)(wsb + (4ull  << 20));   // 4 MB
    float*  t0P     = (float*)(wsb + (8ull  << 20));   // 16 MB (4 split-K parts)
    float*  cb_buf  = (float*)(wsb + (8ull  << 20));   // 32 KB (time-disjoint w/ t0P)
    float*  Opart   = (float*)(wsb + (16ull << 20));   // 8 MB (t0P parts 2-3)
    float*  scP     = (float*)(wsb + (24ull << 20));   // 16 MB (4 parts)
    ushort* h16     = (ushort*)(wsb + (40ull << 20));  // 2 MB
    ushort* ao16    = (ushort*)(wsb + (42ull << 20));  // 2 MB
    float*  qkv_buf = (float*)(wsb + (44ull << 20));   // 6 MB (aliases he16)
    ushort* he16    = (ushort*)(wsb + (44ull << 20));  // 8 MB (44..52)
    float*  ml_buf  = (float*)(wsb + (50ull << 20));   // 256 KB (he16 tail)
    ushort* wT      = (ushort*)(wsb + (52ull << 20));  // 16 MB (52..68)
    ushort* Qb      = (ushort*)(wsb + (62ull << 20));  // 2 MB (wT tail, dead zone)
    ushort* Kb      = (ushort*)(wsb + (64ull << 20));  // 0.5 MB
    ushort* VtG     = (ushort*)(wsb + (65ull << 20));  // 0.5 MB

    auto transp = [&](const float* W, int R, int Cn, int nz, long zs_in, long zs_out) {
        transpose_bf16_kernel<<<dim3(Cn / 64, R / 64, nz), 256, 0, stream>>>(
            W, wT, R, Cn, Cn, zs_in, zs_out);
    };
    auto rmsnorm = [&](const float* xP, int nparts, const float* wn,
                       const float* gw, float* cb) {
        add_rmsnorm_kernel<<<kT, 256, 0, stream>>>(
            xP, nparts, r_buf, wn, h32, h16, r_buf, gw, cb);
    };
    auto attention = [&](const float* qkv_w, const float* o_w) {
        transp(qkv_w, kH, kQKV, 1, 0, 0);
        // qkv: 64x128 tile, grid 12x16 (192 blocks, %8==0)
        mgemm128_kernel<false><<<dim3(kQKV / 128, kT / 64, 1), 512, 0, stream>>>(
            h16, wT, qkv_buf, nullptr, nullptr, kH, kH, kQKV, kH,
            0, 0, 0, 0, 0, 0);
        rope_pack_kernel<<<kT, 256, 0, stream>>>(qkv_buf, positions, Qb, Kb);
        transpose_bf16_kernel<<<dim3(1, kT / 64, kNKV), 256, 0, stream>>>(
            qkv_buf + (kNQ + kNKV) * kD, VtG, kT, kD, kQKV, kD, (long)kD * kT);
        attn_mfma_kernel<<<dim3(kT / 64, kNQ, 2), 256, 0, stream>>>(
            Qb, Kb, VtG, Opart, ml_buf);
        attn_merge_kernel<<<kT, 256, 0, stream>>>(Opart, ml_buf, ao16);
        transp(o_w, kNQ * kD, kH, 1, 0, 0);
        // o: 64x128 tile, split-K z=2 -> t0P parts 0..1
        mgemm128_kernel<false><<<dim3(kH / 128, kT / 64, 2), 512, 0, stream>>>(
            ao16, wT, t0P, nullptr, nullptr, kNQ * kD, kNQ * kD, kH, 512,
            0, 0, 0, 512, 0, kTH);
    };
    auto dense_mlp = [&](const float* gu_w, const float* dn_w) {
        transp(gu_w, kH, 2 * kIDense, 1, 0, 0);
        mgemm128_kernel<true><<<dim3(kIDense / 128, kT / 64, 1), 512, 0, stream>>>(
            h16, wT, nullptr, he16, nullptr, kH, kH, kIDense, kH,
            kIDense, 0, 0, 0, 0, 0);
        transp(dn_w, kIDense, kH, 1, 0, 0);
        mgemm128_kernel<false><<<dim3(kH / 128, kT / 64, 4), 512, 0, stream>>>(
            he16, wT, t0P, nullptr, nullptr, kIDense, kIDense, kH, 1024,
            0, 0, 0, 1024, 0, kTH);
    };

    // h, r = add_rmsnorm(hidden, residual, ln0)
    add_rmsnorm_kernel<<<kT, 256, 0, stream>>>(
        hidden, 1, residual, ln0_w, h32, h16, r_buf, nullptr, nullptr);
    // h = attention0(h) -> t0P[0..1]
    attention(qkv0_w, o0_w);
    // h, r = add_rmsnorm(sum t0P[0..1], r, pa0)  + FUSED router -> cb_buf
    rmsnorm(t0P, 2, pa0_w, gate_w, cb_buf);
    // shortcut = moe(h) (dense, combine-scaled) -> scP[0..3]
    transp(w13, kH, 2 * kIMoe, kE, (long)kH * 2 * kIMoe, (long)kH * 2 * kIMoe);
    mgemm128_kernel<true><<<dim3(kIMoe / 128, kT / 64, kE), 512, 0, stream>>>(
        h16, wT, nullptr, he16, cb_buf, kH, kH, kIDense, kH,
        kIMoe, (long)kH * 2 * kIMoe, kIMoe, 0, kE, 0);
    transp(w2, kE * kIMoe, kH, 1, 0, 0);
    mgemm128_kernel<false><<<dim3(kH / 128, kT / 64, 4), 512, 0, stream>>>(
        he16, wT, scP, nullptr, nullptr, kIDense, kIDense, kH, 1024,
        0, 0, 0, 1024, 0, kTH);
    // h = dense_mlp0(h) -> t0P[0..3]
    dense_mlp(gu0_w, dn0_w);
    // h, r = add_rmsnorm(sum t0P[0..3], r, ln1)
    rmsnorm(t0P, 4, ln1_w, nullptr, nullptr);
    // h = attention1(h) -> t0P[0..1]
    attention(qkv1_w, o1_w);
    // h, r = add_rmsnorm(sum t0P[0..1], r, pa1)
    rmsnorm(t0P, 2, pa1_w, nullptr, nullptr);
    // h = dense_mlp1(h) -> t0P[0..3]
    dense_mlp(gu1_w, dn1_w);
    // out = (sum t0P + sum scP, r)
    final_out_kernel<<<(kT * kH / 4) / 256, 256, 0, stream>>>(t0P, scP, r_buf, out_h);
}

// Round 18
// 316.302 us; speedup vs baseline: 1.0092x; 1.0092x over previous
//
#include <hip/hip_runtime.h>
#include <math.h>

namespace {

constexpr int kT = 1024;
constexpr int kH = 1024;
constexpr int kNQ = 16;
constexpr int kNKV = 4;
constexpr int kD = 64;
constexpr int kQKV = (kNQ + 2 * kNKV) * kD;   // 1536
constexpr int kIDense = 4096;
constexpr int kIMoe = 512;
constexpr int kE = 8;
constexpr float kEps = 1e-6f;
constexpr long kTH = (long)kT * kH;

typedef __attribute__((ext_vector_type(8))) short short8;
typedef __attribute__((ext_vector_type(4))) float f32x4;

__device__ __forceinline__ ushort f2bf(float f) {
    union { float f; uint32_t u; } v; v.f = f;
    uint32_t r = (v.u + 0x7fffu + ((v.u >> 16) & 1u)) >> 16;
    return (ushort)r;
}
__device__ __forceinline__ void gload16(const void* g, void* l) {
    __builtin_amdgcn_global_load_lds(
        (const __attribute__((address_space(1))) void*)g,
        (__attribute__((address_space(3))) void*)l, 16, 0, 0);
}

// ---------------------------------------------------------------------------
// add + RMSNorm with fused nparts-sum; optionally fused MoE router
// ---------------------------------------------------------------------------
__global__ __launch_bounds__(256) void add_rmsnorm_kernel(
    const float* __restrict__ xP, int nparts, const float* __restrict__ res,
    const float* __restrict__ w, float* __restrict__ h32,
    ushort* __restrict__ h16, float* __restrict__ r_out,
    const float* __restrict__ gate_w, float* __restrict__ combine)
{
    __shared__ float red[4];
    __shared__ float gred[4][kE];
    const int t = blockIdx.x;
    const int i = threadIdx.x;
    const size_t base = (size_t)t * kH;
    float4 s = reinterpret_cast<const float4*>(res + base)[i];
    for (int p = 0; p < nparts; p++) {
        float4 a = reinterpret_cast<const float4*>(xP + p * kTH + base)[i];
        s.x += a.x; s.y += a.y; s.z += a.z; s.w += a.w;
    }
    reinterpret_cast<float4*>(r_out + base)[i] = s;
    float ss = s.x * s.x + s.y * s.y + s.z * s.z + s.w * s.w;
    #pragma unroll
    for (int off = 32; off > 0; off >>= 1) ss += __shfl_down(ss, off);
    if ((i & 63) == 0) red[i >> 6] = ss;
    __syncthreads();
    const float tot = red[0] + red[1] + red[2] + red[3];
    const float inv = rsqrtf(tot * (1.0f / kH) + kEps);
    float4 wv = reinterpret_cast<const float4*>(w)[i];
    float4 o = make_float4(s.x * inv * wv.x, s.y * inv * wv.y,
                           s.z * inv * wv.z, s.w * inv * wv.w);
    reinterpret_cast<float4*>(h32 + base)[i] = o;
    ushort4 u;
    u.x = f2bf(o.x); u.y = f2bf(o.y); u.z = f2bf(o.z); u.w = f2bf(o.w);
    reinterpret_cast<ushort4*>(h16 + base)[i] = u;

    if (gate_w != nullptr) {   // fused router (uniform branch)
        float le[kE];
        const float* gw = gate_w + (size_t)(i * 4) * kE;
        #pragma unroll
        for (int e = 0; e < kE; e++)
            le[e] = o.x * gw[e] + o.y * gw[kE + e] +
                    o.z * gw[2 * kE + e] + o.w * gw[3 * kE + e];
        #pragma unroll
        for (int e = 0; e < kE; e++) {
            #pragma unroll
            for (int off = 32; off > 0; off >>= 1)
                le[e] += __shfl_down(le[e], off);
        }
        if ((i & 63) == 0) {
            #pragma unroll
            for (int e = 0; e < kE; e++) gred[i >> 6][e] = le[e];
        }
        __syncthreads();
        if (i == 0) {
            float p[kE];
            float mx = -1e30f;
            #pragma unroll
            for (int e = 0; e < kE; e++) {
                p[e] = gred[0][e] + gred[1][e] + gred[2][e] + gred[3][e];
                mx = fmaxf(mx, p[e]);
            }
            float sum = 0.0f;
            #pragma unroll
            for (int e = 0; e < kE; e++) { p[e] = __expf(p[e] - mx); sum += p[e]; }
            const float invs = 1.0f / sum;
            #pragma unroll
            for (int e = 0; e < kE; e++) p[e] *= invs;
            int i1 = 0;
            #pragma unroll
            for (int e = 1; e < kE; e++) if (p[e] > p[i1]) i1 = e;
            int i2 = (i1 == 0) ? 1 : 0;
            #pragma unroll
            for (int e = 0; e < kE; e++) if (e != i1 && p[e] > p[i2]) i2 = e;
            #pragma unroll
            for (int e = 0; e < kE; e++)
                combine[(size_t)t * kE + e] =
                    (e == i1) ? p[i1] : (e == i2) ? p[i2] : 0.0f;
        }
    }
}

// ---------------------------------------------------------------------------
// Fast transpose + f32 -> bf16
// ---------------------------------------------------------------------------
__global__ __launch_bounds__(256) void transpose_bf16_kernel(
    const float* __restrict__ W, ushort* __restrict__ WT,
    int R, int Cn, int ld_w, long w_z_stride, long wt_z_stride)
{
    __shared__ float tile[64 * 65];
    const int z = blockIdx.z;
    const float* Wz = W + (size_t)z * w_z_stride;
    ushort* WTz = WT + (size_t)z * wt_z_stride;
    const int r0 = blockIdx.y * 64;
    const int c0 = blockIdx.x * 64;
    const int tid = threadIdx.x;
    const int lr = tid >> 4;
    const int lc = (tid & 15) * 4;
    #pragma unroll
    for (int p = 0; p < 4; p++) {
        const int row = p * 16 + lr;
        float4 v = *reinterpret_cast<const float4*>(
            &Wz[(size_t)(r0 + row) * ld_w + c0 + lc]);
        tile[row * 65 + lc + 0] = v.x;
        tile[row * 65 + lc + 1] = v.y;
        tile[row * 65 + lc + 2] = v.z;
        tile[row * 65 + lc + 3] = v.w;
    }
    __syncthreads();
    const int ocl = tid >> 2;
    const int q = tid & 3;
    ushort u[16];
    #pragma unroll
    for (int e = 0; e < 16; e++)
        u[e] = f2bf(tile[(q * 16 + e) * 65 + ocl]);
    ushort* dst = &WTz[(size_t)(c0 + ocl) * R + r0 + q * 16];
    *reinterpret_cast<short8*>(dst) = *reinterpret_cast<short8*>(&u[0]);
    *reinterpret_cast<short8*>(dst + 8) = *reinterpret_cast<short8*>(&u[8]);
}

// ---------------------------------------------------------------------------
// bf16 MFMA GEMM, 64x64 tile, BK=64, 256 thr — (qkv and o GEMMs)
// ---------------------------------------------------------------------------
template <bool GATED>
__global__ __launch_bounds__(256) void mgemm_kernel(
    const ushort* __restrict__ A, const ushort* __restrict__ B,
    float* __restrict__ Cf, ushort* __restrict__ C16,
    const float* __restrict__ scale,
    int lda, int ldb, int ldc, int kc,
    int gate_off_rows, long b_z_stride, int c_z_col, int k_z_off,
    int scale_stride, long c_fstride)
{
    __shared__ __align__(16) ushort As[64 * 64];
    __shared__ __align__(16) ushort Bs[64 * 64];
    __shared__ __align__(16) ushort Us[GATED ? 64 * 64 : 8];

    const int z = blockIdx.z;
    const int gy = gridDim.y;
    const int nf = gridDim.x * gy;
    const int fid = blockIdx.x + gridDim.x * blockIdx.y;
    const int qq = nf >> 3;
    const int id2 = (fid & 7) * qq + (fid >> 3);
    const int m0 = (id2 % gy) * 64;
    const int n0 = (id2 / gy) * 64;

    const int tid = threadIdx.x;
    const ushort* Bz = B + (size_t)z * b_z_stride;
    const int k0 = z * k_z_off;

    const int arow = tid >> 3;
    const int achk = tid & 7;

    const int lane = tid & 63;
    const int wave = tid >> 6;
    const int wr = (wave >> 1) * 32;
    const int wc = (wave & 1) * 32;
    const int lrow = lane & 15;
    const int lg = lane >> 4;

    f32x4 accg[2][2] = {};
    f32x4 accu[2][2] = {};

    for (int kk0 = 0; kk0 < kc; kk0 += 64) {
        const int kbase = k0 + kk0;
        #pragma unroll
        for (int c = 0; c < 2; c++) {
            const int row = c * 32 + arow;
            const int cs = (achk + (row & 7)) & 7;
            gload16(A + (size_t)(m0 + row) * lda + kbase + cs * 8,
                    (char*)As + c * 4096 + tid * 16);
            gload16(Bz + (size_t)(n0 + row) * ldb + kbase + cs * 8,
                    (char*)Bs + c * 4096 + tid * 16);
            if constexpr (GATED)
                gload16(Bz + (size_t)(gate_off_rows + n0 + row) * ldb + kbase + cs * 8,
                        (char*)Us + c * 4096 + tid * 16);
        }
        __syncthreads();

        short8 af[2][2], bfr[2][2];
        #pragma unroll
        for (int mf = 0; mf < 2; mf++)
            #pragma unroll
            for (int kk = 0; kk < 2; kk++) {
                const int r = wr + mf * 16 + lrow;
                const int sl = ((kk * 4 + lg) - (r & 7)) & 7;
                af[mf][kk] = *reinterpret_cast<const short8*>(
                    (const char*)As + r * 128 + sl * 16);
            }
        #pragma unroll
        for (int nf2 = 0; nf2 < 2; nf2++)
            #pragma unroll
            for (int kk = 0; kk < 2; kk++) {
                const int n = wc + nf2 * 16 + lrow;
                const int sl = ((kk * 4 + lg) - (n & 7)) & 7;
                bfr[nf2][kk] = *reinterpret_cast<const short8*>(
                    (const char*)Bs + n * 128 + sl * 16);
            }
        #pragma unroll
        for (int mf = 0; mf < 2; mf++)
            #pragma unroll
            for (int nf2 = 0; nf2 < 2; nf2++)
                #pragma unroll
                for (int kk = 0; kk < 2; kk++)
                    accg[mf][nf2] = __builtin_amdgcn_mfma_f32_16x16x32_bf16(
                        af[mf][kk], bfr[nf2][kk], accg[mf][nf2], 0, 0, 0);
        if constexpr (GATED) {
            short8 uf[2][2];
            #pragma unroll
            for (int nf2 = 0; nf2 < 2; nf2++)
                #pragma unroll
                for (int kk = 0; kk < 2; kk++) {
                    const int n = wc + nf2 * 16 + lrow;
                    const int sl = ((kk * 4 + lg) - (n & 7)) & 7;
                    uf[nf2][kk] = *reinterpret_cast<const short8*>(
                        (const char*)Us + n * 128 + sl * 16);
                }
            #pragma unroll
            for (int mf = 0; mf < 2; mf++)
                #pragma unroll
                for (int nf2 = 0; nf2 < 2; nf2++)
                    #pragma unroll
                    for (int kk = 0; kk < 2; kk++)
                        accu[mf][nf2] = __builtin_amdgcn_mfma_f32_16x16x32_bf16(
                            af[mf][kk], uf[nf2][kk], accu[mf][nf2], 0, 0, 0);
        }
        __syncthreads();
    }

    const int r4 = (lane >> 4) * 4;
    const int cl = lane & 15;
    const int ccol = z * c_z_col;
    float* Cfz = Cf ? Cf + (size_t)z * c_fstride : nullptr;
    #pragma unroll
    for (int mf = 0; mf < 2; mf++) {
        #pragma unroll
        for (int nf2 = 0; nf2 < 2; nf2++) {
            #pragma unroll
            for (int j = 0; j < 4; j++) {
                const int row = m0 + wr + mf * 16 + r4 + j;
                const int col = ccol + n0 + wc + nf2 * 16 + cl;
                if constexpr (GATED) {
                    const float g = accg[mf][nf2][j];
                    const float u = accu[mf][nf2][j];
                    const float sv =
                        scale ? scale[(size_t)row * scale_stride + z] : 1.0f;
                    const float h = (g / (1.0f + __expf(-g))) * u * sv;
                    C16[(size_t)row * ldc + col] = f2bf(h);
                } else {
                    Cfz[(size_t)row * ldc + col] = accg[mf][nf2][j];
                }
            }
        }
    }
}

// ---------------------------------------------------------------------------
// bf16 MFMA GEMM, 64x128 tile, BK=64, 512 thr (8 waves 2m x 4n) — gu/w13/dn/w2
// ---------------------------------------------------------------------------
template <bool GATED>
__global__ __launch_bounds__(512) void mgemm128_kernel(
    const ushort* __restrict__ A, const ushort* __restrict__ B,
    float* __restrict__ Cf, ushort* __restrict__ C16,
    const float* __restrict__ scale,
    int lda, int ldb, int ldc, int kc,
    int gate_off_rows, long b_z_stride, int c_z_col, int k_z_off,
    int scale_stride, long c_fstride)
{
    __shared__ __align__(16) ushort As[64 * 64];
    __shared__ __align__(16) ushort Bs[128 * 64];
    __shared__ __align__(16) ushort Us[GATED ? 128 * 64 : 8];

    const int z = blockIdx.z;
    const int gy = gridDim.y;
    const int nf = gridDim.x * gy;
    const int fid = blockIdx.x + gridDim.x * blockIdx.y;
    const int qq = nf >> 3;
    const int id2 = (fid & 7) * qq + (fid >> 3);
    const int m0 = (id2 % gy) * 64;
    const int n0 = (id2 / gy) * 128;

    const int tid = threadIdx.x;
    const ushort* Bz = B + (size_t)z * b_z_stride;
    const int k0 = z * k_z_off;

    const int sr = tid >> 3;
    const int sc = tid & 7;

    const int lane = tid & 63;
    const int wave = tid >> 6;
    const int wr = (wave >> 2) * 32;
    const int wc = (wave & 3) * 32;
    const int lrow = lane & 15;
    const int lg = lane >> 4;

    f32x4 accg[2][2] = {};
    f32x4 accu[2][2] = {};

    for (int kk0 = 0; kk0 < kc; kk0 += 64) {
        const int kbase = k0 + kk0;
        {
            const int csA = (sc + (sr & 7)) & 7;
            gload16(A + (size_t)(m0 + sr) * lda + kbase + csA * 8,
                    (char*)As + tid * 16);
        }
        #pragma unroll
        for (int c = 0; c < 2; c++) {
            const int row = c * 64 + sr;
            const int cs = (sc + (row & 7)) & 7;
            gload16(Bz + (size_t)(n0 + row) * ldb + kbase + cs * 8,
                    (char*)Bs + c * 8192 + tid * 16);
            if constexpr (GATED)
                gload16(Bz + (size_t)(gate_off_rows + n0 + row) * ldb + kbase + cs * 8,
                        (char*)Us + c * 8192 + tid * 16);
        }
        __syncthreads();

        short8 af[2][2], bfr[2][2];
        #pragma unroll
        for (int mf = 0; mf < 2; mf++)
            #pragma unroll
            for (int kk = 0; kk < 2; kk++) {
                const int r = wr + mf * 16 + lrow;
                const int sl = ((kk * 4 + lg) - (r & 7)) & 7;
                af[mf][kk] = *reinterpret_cast<const short8*>(
                    (const char*)As + r * 128 + sl * 16);
            }
        #pragma unroll
        for (int nf2 = 0; nf2 < 2; nf2++)
            #pragma unroll
            for (int kk = 0; kk < 2; kk++) {
                const int n = wc + nf2 * 16 + lrow;
                const int sl = ((kk * 4 + lg) - (n & 7)) & 7;
                bfr[nf2][kk] = *reinterpret_cast<const short8*>(
                    (const char*)Bs + n * 128 + sl * 16);
            }
        #pragma unroll
        for (int mf = 0; mf < 2; mf++)
            #pragma unroll
            for (int nf2 = 0; nf2 < 2; nf2++)
                #pragma unroll
                for (int kk = 0; kk < 2; kk++)
                    accg[mf][nf2] = __builtin_amdgcn_mfma_f32_16x16x32_bf16(
                        af[mf][kk], bfr[nf2][kk], accg[mf][nf2], 0, 0, 0);
        if constexpr (GATED) {
            short8 uf[2][2];
            #pragma unroll
            for (int nf2 = 0; nf2 < 2; nf2++)
                #pragma unroll
                for (int kk = 0; kk < 2; kk++) {
                    const int n = wc + nf2 * 16 + lrow;
                    const int sl = ((kk * 4 + lg) - (n & 7)) & 7;
                    uf[nf2][kk] = *reinterpret_cast<const short8*>(
                        (const char*)Us + n * 128 + sl * 16);
                }
            #pragma unroll
            for (int mf = 0; mf < 2; mf++)
                #pragma unroll
                for (int nf2 = 0; nf2 < 2; nf2++)
                    #pragma unroll
                    for (int kk = 0; kk < 2; kk++)
                        accu[mf][nf2] = __builtin_amdgcn_mfma_f32_16x16x32_bf16(
                            af[mf][kk], uf[nf2][kk], accu[mf][nf2], 0, 0, 0);
        }
        __syncthreads();
    }

    const int r4 = (lane >> 4) * 4;
    const int cl = lane & 15;
    const int ccol = z * c_z_col;
    float* Cfz = Cf ? Cf + (size_t)z * c_fstride : nullptr;
    #pragma unroll
    for (int mf = 0; mf < 2; mf++) {
        #pragma unroll
        for (int nf2 = 0; nf2 < 2; nf2++) {
            #pragma unroll
            for (int j = 0; j < 4; j++) {
                const int row = m0 + wr + mf * 16 + r4 + j;
                const int col = ccol + n0 + wc + nf2 * 16 + cl;
                if constexpr (GATED) {
                    const float g = accg[mf][nf2][j];
                    const float u = accu[mf][nf2][j];
                    const float sv =
                        scale ? scale[(size_t)row * scale_stride + z] : 1.0f;
                    const float h = (g / (1.0f + __expf(-g))) * u * sv;
                    C16[(size_t)row * ldc + col] = f2bf(h);
                } else {
                    Cfz[(size_t)row * ldc + col] = accg[mf][nf2][j];
                }
            }
        }
    }
}

// ---------------------------------------------------------------------------
// RoPE + bf16 pack
// ---------------------------------------------------------------------------
__global__ __launch_bounds__(256) void rope_pack_kernel(
    const float* __restrict__ qkv, const int* __restrict__ positions,
    ushort* __restrict__ Qb, ushort* __restrict__ Kb)
{
    const int t = blockIdx.x;
    const float pos = (float)positions[t];
    for (int item = threadIdx.x; item < (kNQ + kNKV) * 32; item += 256) {
        const int head = item >> 5;
        const int i = item & 31;
        const float inv_freq = powf(10000.0f, -(float)i * (1.0f / 32.0f));
        const float f = pos * inv_freq;
        float sv, cv;
        sincosf(f, &sv, &cv);
        const size_t off = (size_t)t * kQKV + head * kD;
        const float x1 = qkv[off + i];
        const float x2 = qkv[off + 32 + i];
        const float r1 = x1 * cv - x2 * sv;
        const float r2 = x2 * cv + x1 * sv;
        if (head < kNQ) {
            ushort* q = Qb + ((size_t)head * kT + t) * kD;
            q[i] = f2bf(r1 * 0.125f);
            q[i + 32] = f2bf(r2 * 0.125f);
        } else {
            ushort* k = Kb + ((size_t)(head - kNQ) * kT + t) * kD;
            k[i] = f2bf(r1);
            k[i + 32] = f2bf(r2);
        }
    }
}

// ---------------------------------------------------------------------------
// MFMA flash attention, KV-SPLIT (z=2) — r12 structure
// ---------------------------------------------------------------------------
__global__ __launch_bounds__(256) void attn_mfma_kernel(
    const ushort* __restrict__ Qb, const ushort* __restrict__ Kb,
    const ushort* __restrict__ Vt, float* __restrict__ Opart,
    float* __restrict__ mlpart)
{
    __shared__ __align__(16) ushort Qs[64 * 64];
    __shared__ __align__(16) ushort Ks[64 * 64];
    __shared__ __align__(16) ushort Vs[64 * 64];
    __shared__ __align__(16) ushort Ps[64 * 64];
    const int tid = threadIdx.x;
    const int qbi = (int)gridDim.x - 1 - blockIdx.x;
    const int qb = qbi * 64;
    const int hq = blockIdx.y;
    const int zp = blockIdx.z;
    const int kvh = hq >> 2;

    const int nt = qbi + 1;
    const int halfc = (nt + 1) >> 1;
    const int sbeg = zp ? halfc : 0;
    const int send = zp ? nt : halfc;

    float* Oz = Opart + (((size_t)zp * kNQ + hq) * kT + qb) * kD;
    float* mlz = mlpart + (((size_t)zp * kNQ + hq) * kT + qb) * 2;

    if (sbeg >= send) {
        for (int i = tid; i < 64 * kD; i += 256) Oz[(i >> 6) * kD + (i & 63)] = 0.f;
        for (int i = tid; i < 64; i += 256) { mlz[i * 2] = -1e30f; mlz[i * 2 + 1] = 0.f; }
        return;
    }

    const int lane = tid & 63;
    const int wave = tid >> 6;
    const int lrow = lane & 15;
    const int g = lane >> 4;
    const int srow = tid >> 3;
    const int sx = tid & 7;
    const ushort* Qg = Qb + ((size_t)hq * kT + qb) * kD;
    const ushort* Kg = Kb + (size_t)kvh * kT * kD;
    const ushort* Vg = Vt + (size_t)kvh * kD * kT;
    const int xr = (lrow & 7) << 4;

    #pragma unroll
    for (int c = 0; c < 2; c++) {
        const int row = c * 32 + srow;
        gload16(Qg + (size_t)row * kD + ((sx ^ (row & 7)) * 8),
                (char*)Qs + c * 4096 + tid * 16);
    }
    __syncthreads();
    short8 qf[2];
    #pragma unroll
    for (int kk = 0; kk < 2; kk++)
        qf[kk] = *reinterpret_cast<const short8*>(
            (const char*)Qs + (16 * wave + lrow) * 128 + ((kk * 64 + g * 16) ^ xr));

    f32x4 oacc[4] = {};
    float mrow = -1e30f, lsum = 0.0f;

    for (int ti = sbeg; ti < send; ++ti) {
        const int s0 = ti * 64;
        __syncthreads();
        #pragma unroll
        for (int c = 0; c < 2; c++) {
            const int row = c * 32 + srow;
            gload16(Kg + (size_t)(s0 + row) * kD + ((sx ^ (row & 7)) * 8),
                    (char*)Ks + c * 4096 + tid * 16);
            gload16(Vg + (size_t)row * kT + s0 + ((sx ^ (row & 7)) * 8),
                    (char*)Vs + c * 4096 + tid * 16);
        }
        __syncthreads();

        f32x4 sacc[4] = {};
        #pragma unroll
        for (int nf = 0; nf < 4; nf++) {
            #pragma unroll
            for (int kk = 0; kk < 2; kk++) {
                short8 kf = *reinterpret_cast<const short8*>(
                    (const char*)Ks + (nf * 16 + lrow) * 128 + ((kk * 64 + g * 16) ^ xr));
                sacc[nf] = __builtin_amdgcn_mfma_f32_16x16x32_bf16(
                    kf, qf[kk], sacc[nf], 0, 0, 0);
            }
        }

        const bool diag = (s0 == qb);
        float pv[16];
        float mloc = -1e30f;
        #pragma unroll
        for (int nf = 0; nf < 4; nf++)
            #pragma unroll
            for (int j = 0; j < 4; j++) {
                float s = sacc[nf][j];
                if (diag && (nf * 16 + g * 4 + j > 16 * wave + lrow)) s = -1e30f;
                pv[nf * 4 + j] = s;
                mloc = fmaxf(mloc, s);
            }
        mloc = fmaxf(mloc, __shfl_xor(mloc, 16));
        mloc = fmaxf(mloc, __shfl_xor(mloc, 32));
        const float mnew = fmaxf(mrow, mloc);
        const float alpha = __expf(mrow - mnew);
        float psum = 0.0f;
        #pragma unroll
        for (int j = 0; j < 16; j++) { pv[j] = __expf(pv[j] - mnew); psum += pv[j]; }
        psum += __shfl_xor(psum, 16);
        psum += __shfl_xor(psum, 32);
        lsum = lsum * alpha + psum;
        mrow = mnew;

        const int prow = 16 * wave + lrow;
        #pragma unroll
        for (int nf = 0; nf < 4; nf++)
            #pragma unroll
            for (int jp = 0; jp < 2; jp++) {
                uint32_t pk = (uint32_t)f2bf(pv[nf * 4 + jp * 2]) |
                              ((uint32_t)f2bf(pv[nf * 4 + jp * 2 + 1]) << 16);
                *reinterpret_cast<uint32_t*>(
                    (char*)Ps + prow * 128 + ((nf * 32 + g * 8 + jp * 4) ^ xr)) = pk;
            }

        float aj[4];
        #pragma unroll
        for (int j = 0; j < 4; j++) aj[j] = __shfl(alpha, g * 4 + j);
        #pragma unroll
        for (int nf = 0; nf < 4; nf++)
            #pragma unroll
            for (int j = 0; j < 4; j++) oacc[nf][j] *= aj[j];

        short8 paf[2];
        #pragma unroll
        for (int kk = 0; kk < 2; kk++)
            paf[kk] = *reinterpret_cast<const short8*>(
                (const char*)Ps + prow * 128 + ((kk * 64 + g * 16) ^ xr));
        #pragma unroll
        for (int nf = 0; nf < 4; nf++)
            #pragma unroll
            for (int kk = 0; kk < 2; kk++) {
                short8 vf = *reinterpret_cast<const short8*>(
                    (const char*)Vs + (nf * 16 + lrow) * 128 + ((kk * 64 + g * 16) ^ xr));
                oacc[nf] = __builtin_amdgcn_mfma_f32_16x16x32_bf16(
                    paf[kk], vf, oacc[nf], 0, 0, 0);
            }
    }

    #pragma unroll
    for (int nf = 0; nf < 4; nf++)
        #pragma unroll
        for (int j = 0; j < 4; j++)
            Oz[(16 * wave + g * 4 + j) * kD + nf * 16 + lrow] = oacc[nf][j];
    if (g == 0) {
        mlz[(16 * wave + lrow) * 2 + 0] = mrow;
        mlz[(16 * wave + lrow) * 2 + 1] = lsum;
    }
}

// ---------------------------------------------------------------------------
// Merge 2 KV-split partials -> normalized bf16 attn output
// ---------------------------------------------------------------------------
__global__ __launch_bounds__(256) void attn_merge_kernel(
    const float* __restrict__ Opart, const float* __restrict__ mlpart,
    ushort* __restrict__ attn_o)
{
    const int trow = blockIdx.x;
    const int tid = threadIdx.x;
    const int head = tid >> 4;
    const int c4 = (tid & 15) * 4;
    const size_t i0 = ((size_t)head * kT + trow);
    const size_t i1 = (((size_t)kNQ + head) * kT + trow);
    const float m0 = mlpart[i0 * 2], l0 = mlpart[i0 * 2 + 1];
    const float m1 = mlpart[i1 * 2], l1 = mlpart[i1 * 2 + 1];
    const float m = fmaxf(m0, m1);
    const float e0 = __expf(m0 - m), e1 = __expf(m1 - m);
    const float inv = 1.0f / (l0 * e0 + l1 * e1);
    float4 a = *reinterpret_cast<const float4*>(&Opart[i0 * kD + c4]);
    float4 b = *reinterpret_cast<const float4*>(&Opart[i1 * kD + c4]);
    ushort4 u;
    u.x = f2bf((a.x * e0 + b.x * e1) * inv);
    u.y = f2bf((a.y * e0 + b.y * e1) * inv);
    u.z = f2bf((a.z * e0 + b.z * e1) * inv);
    u.w = f2bf((a.w * e0 + b.w * e1) * inv);
    *reinterpret_cast<ushort4*>(
        &attn_o[(size_t)trow * (kNQ * kD) + head * kD + c4]) = u;
}

// ---------------------------------------------------------------------------
// final: out[0:TH] = sum(mlpP[0..3]) + sum(scP[0..3]); out[TH:] = r
// ---------------------------------------------------------------------------
__global__ __launch_bounds__(256) void final_out_kernel(
    const float* __restrict__ mlpP, const float* __restrict__ scP,
    const float* __restrict__ r, float* __restrict__ out)
{
    const int i = blockIdx.x * 256 + threadIdx.x;
    float4 s = make_float4(0.f, 0.f, 0.f, 0.f);
    #pragma unroll
    for (int p = 0; p < 4; p++) {
        float4 a = reinterpret_cast<const float4*>(mlpP + p * kTH)[i];
        float4 b = reinterpret_cast<const float4*>(scP + p * kTH)[i];
        s.x += a.x + b.x; s.y += a.y + b.y; s.z += a.z + b.z; s.w += a.w + b.w;
    }
    reinterpret_cast<float4*>(out)[i] = s;
    reinterpret_cast<float4*>(out + kTH)[i] =
        reinterpret_cast<const float4*>(r)[i];
}

}  // namespace

extern "C" void kernel_launch(void* const* d_in, const int* in_sizes, int n_in,
                              void* d_out, int out_size, void* d_ws, size_t ws_size,
                              hipStream_t stream) {
    (void)in_sizes; (void)n_in; (void)out_size; (void)ws_size;
    const float* hidden   = (const float*)d_in[0];
    const float* residual = (const float*)d_in[1];
    const int*   positions= (const int*)d_in[2];
    const float* ln0_w    = (const float*)d_in[3];
    const float* pa0_w    = (const float*)d_in[4];
    const float* ln1_w    = (const float*)d_in[5];
    const float* pa1_w    = (const float*)d_in[6];
    const float* qkv0_w   = (const float*)d_in[7];
    const float* o0_w     = (const float*)d_in[8];
    const float* qkv1_w   = (const float*)d_in[9];
    const float* o1_w     = (const float*)d_in[10];
    const float* gu0_w    = (const float*)d_in[11];
    const float* dn0_w    = (const float*)d_in[12];
    const float* gu1_w    = (const float*)d_in[13];
    const float* dn1_w    = (const float*)d_in[14];
    const float* gate_w   = (const float*)d_in[15];
    const float* w13      = (const float*)d_in[16];
    const float* w2       = (const float*)d_in[17];
    float* out_h = (float*)d_out;

    char* wsb = (char*)d_ws;
    float*  r_buf   = (float*)(wsb + (0ull  << 20));   // 4 MB
    float*  h32     = (float*)(wsb + (4ull  << 20));   // 4 MB
    float*  t0P     = (float*)(wsb + (8ull  << 20));   // 16 MB (4 split-K parts)
    float*  cb_buf  = (float*)(wsb + (8ull  << 20));   // 32 KB (time-disjoint w/ t0P)
    float*  Opart   = (float*)(wsb + (16ull << 20));   // 8 MB (t0P parts 2-3)
    float*  scP     = (float*)(wsb + (24ull << 20));   // 16 MB (4 parts)
    ushort* h16     = (ushort*)(wsb + (40ull << 20));  // 2 MB
    ushort* ao16    = (ushort*)(wsb + (42ull << 20));  // 2 MB
    float*  qkv_buf = (float*)(wsb + (44ull << 20));   // 6 MB (aliases he16)
    ushort* he16    = (ushort*)(wsb + (44ull << 20));  // 8 MB (44..52)
    float*  ml_buf  = (float*)(wsb + (50ull << 20));   // 256 KB (he16 tail)
    ushort* wT      = (ushort*)(wsb + (52ull << 20));  // 16 MB (52..68)
    ushort* Qb      = (ushort*)(wsb + (62ull << 20));  // 2 MB (wT tail, dead zone)
    ushort* Kb      = (ushort*)(wsb + (64ull << 20));  // 0.5 MB
    ushort* VtG     = (ushort*)(wsb + (65ull << 20));  // 0.5 MB

    auto transp = [&](const float* W, int R, int Cn, int nz, long zs_in, long zs_out) {
        transpose_bf16_kernel<<<dim3(Cn / 64, R / 64, nz), 256, 0, stream>>>(
            W, wT, R, Cn, Cn, zs_in, zs_out);
    };
    auto rmsnorm = [&](const float* xP, int nparts, const float* wn,
                       const float* gw, float* cb) {
        add_rmsnorm_kernel<<<kT, 256, 0, stream>>>(
            xP, nparts, r_buf, wn, h32, h16, r_buf, gw, cb);
    };
    auto attention = [&](const float* qkv_w, const float* o_w) {
        transp(qkv_w, kH, kQKV, 1, 0, 0);
        mgemm_kernel<false><<<dim3(kQKV / 64, kT / 64, 1), 256, 0, stream>>>(
            h16, wT, qkv_buf, nullptr, nullptr, kH, kH, kQKV, kH,
            0, 0, 0, 0, 0, 0);
        rope_pack_kernel<<<kT, 256, 0, stream>>>(qkv_buf, positions, Qb, Kb);
        transpose_bf16_kernel<<<dim3(1, kT / 64, kNKV), 256, 0, stream>>>(
            qkv_buf + (kNQ + kNKV) * kD, VtG, kT, kD, kQKV, kD, (long)kD * kT);
        attn_mfma_kernel<<<dim3(kT / 64, kNQ, 2), 256, 0, stream>>>(
            Qb, Kb, VtG, Opart, ml_buf);
        attn_merge_kernel<<<kT, 256, 0, stream>>>(Opart, ml_buf, ao16);
        transp(o_w, kNQ * kD, kH, 1, 0, 0);
        mgemm_kernel<false><<<dim3(kH / 64, kT / 64, 2), 256, 0, stream>>>(
            ao16, wT, t0P, nullptr, nullptr, kNQ * kD, kNQ * kD, kH, 512,
            0, 0, 0, 512, 0, kTH);
    };
    auto dense_mlp = [&](const float* gu_w, const float* dn_w) {
        transp(gu_w, kH, 2 * kIDense, 1, 0, 0);
        mgemm128_kernel<true><<<dim3(kIDense / 128, kT / 64, 1), 512, 0, stream>>>(
            h16, wT, nullptr, he16, nullptr, kH, kH, kIDense, kH,
            kIDense, 0, 0, 0, 0, 0);
        transp(dn_w, kIDense, kH, 1, 0, 0);
        mgemm128_kernel<false><<<dim3(kH / 128, kT / 64, 4), 512, 0, stream>>>(
            he16, wT, t0P, nullptr, nullptr, kIDense, kIDense, kH, 1024,
            0, 0, 0, 1024, 0, kTH);
    };

    // h, r = add_rmsnorm(hidden, residual, ln0)
    add_rmsnorm_kernel<<<kT, 256, 0, stream>>>(
        hidden, 1, residual, ln0_w, h32, h16, r_buf, nullptr, nullptr);
    // h = attention0(h) -> t0P[0..1]
    attention(qkv0_w, o0_w);
    // h, r = add_rmsnorm(sum t0P[0..1], r, pa0)  + FUSED router -> cb_buf
    rmsnorm(t0P, 2, pa0_w, gate_w, cb_buf);
    // shortcut = moe(h) (dense, combine-scaled) -> scP[0..3]
    transp(w13, kH, 2 * kIMoe, kE, (long)kH * 2 * kIMoe, (long)kH * 2 * kIMoe);
    mgemm128_kernel<true><<<dim3(kIMoe / 128, kT / 64, kE), 512, 0, stream>>>(
        h16, wT, nullptr, he16, cb_buf, kH, kH, kIDense, kH,
        kIMoe, (long)kH * 2 * kIMoe, kIMoe, 0, kE, 0);
    transp(w2, kE * kIMoe, kH, 1, 0, 0);
    mgemm128_kernel<false><<<dim3(kH / 128, kT / 64, 4), 512, 0, stream>>>(
        he16, wT, scP, nullptr, nullptr, kIDense, kIDense, kH, 1024,
        0, 0, 0, 1024, 0, kTH);
    // h = dense_mlp0(h) -> t0P[0..3]
    dense_mlp(gu0_w, dn0_w);
    // h, r = add_rmsnorm(sum t0P[0..3], r, ln1)
    rmsnorm(t0P, 4, ln1_w, nullptr, nullptr);
    // h = attention1(h) -> t0P[0..1]
    attention(qkv1_w, o1_w);
    // h, r = add_rmsnorm(sum t0P[0..1], r, pa1)
    rmsnorm(t0P, 2, pa1_w, nullptr, nullptr);
    // h = dense_mlp1(h) -> t0P[0..3]
    dense_mlp(gu1_w, dn1_w);
    // out = (sum t0P + sum scP, r)
    final_out_kernel<<<(kT * kH / 4) / 256, 256, 0, stream>>>(t0P, scP, r_buf, out_h);
}